// Round 18
// baseline (55.962 us; speedup 1.0000x reference)
//
#include <hip/hip_runtime.h>

// Bahdanau additive attention, S=T=512, DU=DT=512, D=1024, fp32.
// score[t,s] = b_s + sum_d w[d]*tanh(A[s,d]+B[t,d]);  out = softmax_s(score) @ rnn
// tanh(x) = 1 - 2/(exp(2x)+1); const shift drops under softmax.
// exp2(C2*(a+b)) = EA[s,d]*EB[t,d]. k1 writes TRANSPOSED partials A^T[d][s];
// k2 staging applies exp2(a0+sumf*a1) (k1b fused). k2 batches 4 d-steps into
// ONE rcp, packed f32x2 cells. k1/k4 use MFMA with bf16 hi/lo split.
// R7 (rule #20): hot loops use NAMED scalars/vectors, constant indices only.
// R12: k2 not slot-bound. R13: not occupancy-bound (nz=8). R16: k1b fusion won.
// R17: k2 LDS DOUBLE-BUFFER, one barrier/chunk, write-after-compute.
// (R17 retry: no token-pasting in K2P — '0.RR' lexes as a pp-number.)
// ws layout (floats): A0T|A1T|B0T|B1T (4x512K) | P[8][256K] | wgt[256K] = 17.8 MB

#define C2F 2.8853900817779268f   // 2*log2(e)

typedef __attribute__((ext_vector_type(8))) short short8;
typedef __attribute__((ext_vector_type(4))) float f32x4;
typedef __attribute__((ext_vector_type(2))) float f32x2;

__device__ __forceinline__ unsigned short bf16_rne(float f) {
    unsigned u = __builtin_bit_cast(unsigned, f);
    unsigned r = (u + 0x7FFFu + ((u >> 16) & 1u)) >> 16;
    return (unsigned short)r;
}
__device__ __forceinline__ float bf16_f(unsigned short h) {
    unsigned u = ((unsigned)h) << 16;
    return __builtin_bit_cast(float, u);
}
__device__ __forceinline__ f32x2 splat2(float s) {
    f32x2 r; r.x = s; r.y = s; return r;
}

// ---- k1_mfma: partial GEMM via MFMA, TRANSPOSED output X^T[j][i].
// i in [0,1024): i<512 -> A (in=rnn), else B (in=tgt, +bias last kz).
__global__ __launch_bounds__(256, 4) void k1_mfma(
    const float* __restrict__ rnn, const float* __restrict__ tgt,
    const float* __restrict__ W, const float* __restrict__ bl,
    float* __restrict__ Abuf, float* __restrict__ Bbuf, int ksplit)
{
    __shared__ unsigned short Xh[64][40], Xl[64][40], Wh[64][40], Wl[64][40];
    const int j0 = blockIdx.x * 64;
    const int i0 = blockIdx.y * 64;
    const int kz = blockIdx.z;
    const int klen = 512 / ksplit;
    const int kbase = kz * klen;
    const bool isB = (i0 >= 512);
    const float* __restrict__ X = isB ? tgt : rnn;
    const int irow0 = isB ? (i0 - 512) : i0;
    const int koff = isB ? 512 : 0;
    const int tid = threadIdx.x;
    const int lane = tid & 63;
    const int wv = tid >> 6;
    const int isub = (wv & 1) * 32;
    const int jsub = (wv >> 1) * 32;
    const int srow = tid >> 2;
    const int skq  = tid & 3;
    const float* __restrict__ xp = X + (size_t)(irow0 + srow) * 512 + kbase + skq * 8;
    const float* __restrict__ wp = W + (size_t)(j0 + srow) * 1024 + koff + kbase + skq * 8;
    const int frow = lane & 15;
    const int fk   = (lane >> 4) * 8;
    f32x4 acc00 = {0.f,0.f,0.f,0.f}, acc01 = {0.f,0.f,0.f,0.f};
    f32x4 acc10 = {0.f,0.f,0.f,0.f}, acc11 = {0.f,0.f,0.f,0.f};
    float4 xv0 = *(const float4*)(xp);
    float4 xv1 = *(const float4*)(xp + 4);
    float4 wv0 = *(const float4*)(wp);
    float4 wv1 = *(const float4*)(wp + 4);
    for (int k0 = 0; k0 < klen; k0 += 32) {
        __syncthreads();
        {
            short8 xh8, xl8, wh8, wl8;
            const float xf[8] = {xv0.x, xv0.y, xv0.z, xv0.w, xv1.x, xv1.y, xv1.z, xv1.w};
            const float wf[8] = {wv0.x, wv0.y, wv0.z, wv0.w, wv1.x, wv1.y, wv1.z, wv1.w};
            #pragma unroll
            for (int e = 0; e < 8; ++e) {
                const unsigned short xh = bf16_rne(xf[e]);
                const unsigned short wh = bf16_rne(wf[e]);
                xh8[e] = (short)xh;
                wh8[e] = (short)wh;
                xl8[e] = (short)bf16_rne(xf[e] - bf16_f(xh));
                wl8[e] = (short)bf16_rne(wf[e] - bf16_f(wh));
            }
            *(short8*)&Xh[srow][skq * 8] = xh8;
            *(short8*)&Xl[srow][skq * 8] = xl8;
            *(short8*)&Wh[srow][skq * 8] = wh8;
            *(short8*)&Wl[srow][skq * 8] = wl8;
        }
        __syncthreads();
        if (k0 + 32 < klen) {
            xv0 = *(const float4*)(xp + k0 + 32);
            xv1 = *(const float4*)(xp + k0 + 36);
            wv0 = *(const float4*)(wp + k0 + 32);
            wv1 = *(const float4*)(wp + k0 + 36);
        }
        const short8 ah0 = *(const short8*)&Xh[isub + frow][fk];
        const short8 ah1 = *(const short8*)&Xh[isub + 16 + frow][fk];
        const short8 bh0 = *(const short8*)&Wh[jsub + frow][fk];
        const short8 bh1 = *(const short8*)&Wh[jsub + 16 + frow][fk];
        acc00 = __builtin_amdgcn_mfma_f32_16x16x32_bf16(ah0, bh0, acc00, 0, 0, 0);
        acc01 = __builtin_amdgcn_mfma_f32_16x16x32_bf16(ah0, bh1, acc01, 0, 0, 0);
        acc10 = __builtin_amdgcn_mfma_f32_16x16x32_bf16(ah1, bh0, acc10, 0, 0, 0);
        acc11 = __builtin_amdgcn_mfma_f32_16x16x32_bf16(ah1, bh1, acc11, 0, 0, 0);
        const short8 al0 = *(const short8*)&Xl[isub + frow][fk];
        const short8 al1 = *(const short8*)&Xl[isub + 16 + frow][fk];
        acc00 = __builtin_amdgcn_mfma_f32_16x16x32_bf16(al0, bh0, acc00, 0, 0, 0);
        acc01 = __builtin_amdgcn_mfma_f32_16x16x32_bf16(al0, bh1, acc01, 0, 0, 0);
        acc10 = __builtin_amdgcn_mfma_f32_16x16x32_bf16(al1, bh0, acc10, 0, 0, 0);
        acc11 = __builtin_amdgcn_mfma_f32_16x16x32_bf16(al1, bh1, acc11, 0, 0, 0);
        const short8 bl0 = *(const short8*)&Wl[jsub + frow][fk];
        const short8 bl1 = *(const short8*)&Wl[jsub + 16 + frow][fk];
        acc00 = __builtin_amdgcn_mfma_f32_16x16x32_bf16(ah0, bl0, acc00, 0, 0, 0);
        acc01 = __builtin_amdgcn_mfma_f32_16x16x32_bf16(ah0, bl1, acc01, 0, 0, 0);
        acc10 = __builtin_amdgcn_mfma_f32_16x16x32_bf16(ah1, bl0, acc10, 0, 0, 0);
        acc11 = __builtin_amdgcn_mfma_f32_16x16x32_bf16(ah1, bl1, acc11, 0, 0, 0);
    }
    const int orow = (lane >> 4) * 4;
    const int ocol = lane & 15;
    float* __restrict__ dst = (isB ? Bbuf : Abuf) + (size_t)kz * 524288;
    const bool addb = isB && (kz == ksplit - 1);
#define K1ST(ACC, MT, NT) do {                                            \
    const int jl = jsub + (NT)*16 + ocol;                                 \
    const float bb = addb ? bl[j0 + jl] : 0.f;                            \
    const int il = isub + (MT)*16 + orow;                                 \
    float4 o;                                                             \
    o.x = (ACC[0] + bb) * C2F;                                            \
    o.y = (ACC[1] + bb) * C2F;                                            \
    o.z = (ACC[2] + bb) * C2F;                                            \
    o.w = (ACC[3] + bb) * C2F;                                            \
    *(float4*)(dst + (size_t)(j0 + jl) * 512 + irow0 + il) = o;           \
} while (0)
    K1ST(acc00, 0, 0); K1ST(acc01, 0, 1); K1ST(acc10, 1, 0); K1ST(acc11, 1, 1);
#undef K1ST
}

// ---- k2 (hot): P[z][t][s] = sum_{d in chunk z} w[d] / (EA[s,d]*EB[t,d] + 1) ----
// Double-buffered LDS, ONE barrier per 32-d chunk. Per phase:
// barrier -> issue global loads (chunk c+1) -> compute buf[cur] (chunk c)
// -> exp2+write buf[cur^1] (chunk c+1). Buffer choice is compile-time.
// K2P references fixed locals A_0..A_3 / B_0..B_3 declared by K2COMP (no pasting).
#define K2P(ACC, PP, RR) do {                                                  \
    const f32x2 e0_ = __builtin_elementwise_fma(A_0.PP, splat2(B_0.RR), one2); \
    const f32x2 e1_ = __builtin_elementwise_fma(A_1.PP, splat2(B_1.RR), one2); \
    const f32x2 e2_ = __builtin_elementwise_fma(A_2.PP, splat2(B_2.RR), one2); \
    const f32x2 e3_ = __builtin_elementwise_fma(A_3.PP, splat2(B_3.RR), one2); \
    const f32x2 l01_ = e0_ * e1_;                                              \
    const f32x2 l23_ = e2_ * e3_;                                              \
    const f32x2 n01_ = __builtin_elementwise_fma(wx2, e1_, wy2 * e0_);         \
    const f32x2 n23_ = __builtin_elementwise_fma(wz2, e3_, ww2 * e2_);         \
    const f32x2 N_   = __builtin_elementwise_fma(n01_, l23_, n23_ * l01_);     \
    const f32x2 D_   = l01_ * l23_;                                            \
    f32x2 rd_;                                                                 \
    rd_.x = __builtin_amdgcn_rcpf(D_.x);                                       \
    rd_.y = __builtin_amdgcn_rcpf(D_.y);                                       \
    ACC = __builtin_elementwise_fma(N_, rd_, ACC);                             \
} while (0)

#define K2EXP(P0, P1) __builtin_amdgcn_exp2f(__builtin_fmaf(sumf, (P1), (P0)))

// issue global loads for chunk CN into the p-registers
#define K2LOAD(CN) do {                                                        \
    const size_t off_ = (size_t)(CN) * 32 * 512;                               \
    pa00 = *(const float4*)(Ar0 + off_);                                       \
    pa01 = *(const float4*)(Ar0 + off_ + 4);                                   \
    pa10 = *(const float4*)(Ar1 + off_);                                       \
    pa11 = *(const float4*)(Ar1 + off_ + 4);                                   \
    pb00 = *(const float4*)(Br0 + off_);                                       \
    pb01 = *(const float4*)(Br0 + off_ + 4);                                   \
    pb10 = *(const float4*)(Br1 + off_);                                       \
    pb11 = *(const float4*)(Br1 + off_ + 4);                                   \
} while (0)

// exp2-transform p-registers and store into buffer AT/BT (plain macro args)
#define K2WRITE(AT, BT) do {                                                   \
    float4 ea0, ea1, eb0, eb1;                                                 \
    ea0.x = K2EXP(pa00.x, pa10.x);                                             \
    ea0.y = K2EXP(pa00.y, pa10.y);                                             \
    ea0.z = K2EXP(pa00.z, pa10.z);                                             \
    ea0.w = K2EXP(pa00.w, pa10.w);                                             \
    ea1.x = K2EXP(pa01.x, pa11.x);                                             \
    ea1.y = K2EXP(pa01.y, pa11.y);                                             \
    ea1.z = K2EXP(pa01.z, pa11.z);                                             \
    ea1.w = K2EXP(pa01.w, pa11.w);                                             \
    eb0.x = K2EXP(pb00.x, pb10.x);                                             \
    eb0.y = K2EXP(pb00.y, pb10.y);                                             \
    eb0.z = K2EXP(pb00.z, pb10.z);                                             \
    eb0.w = K2EXP(pb00.w, pb10.w);                                             \
    eb1.x = K2EXP(pb01.x, pb11.x);                                             \
    eb1.y = K2EXP(pb01.y, pb11.y);                                             \
    eb1.z = K2EXP(pb01.z, pb11.z);                                             \
    eb1.w = K2EXP(pb01.w, pb11.w);                                             \
    *(float4*)&AT[drow][sc8]     = ea0;                                        \
    *(float4*)&AT[drow][sc8 + 4] = ea1;                                        \
    *(float4*)&BT[drow][sc8]     = eb0;                                        \
    *(float4*)&BT[drow][sc8 + 4] = eb1;                                        \
} while (0)

// compute one 32-d chunk (weight base WB) from buffers AT/BT
#define K2COMP(AT, BT, WB) do {                                                \
    for (int dd = 0; dd < 32; dd += 4) {                                       \
        const float4 wa = *(const float4*)&wl[(WB) + dd];                      \
        const f32x2 wx2 = splat2(wa.x);                                        \
        const f32x2 wy2 = splat2(wa.y);                                        \
        const f32x2 wz2 = splat2(wa.z);                                        \
        const f32x2 ww2 = splat2(wa.w);                                        \
        const f32x4 A_0 = *(const f32x4*)&AT[dd + 0][tj * 4];                  \
        const f32x4 A_1 = *(const f32x4*)&AT[dd + 1][tj * 4];                  \
        const f32x4 A_2 = *(const f32x4*)&AT[dd + 2][tj * 4];                  \
        const f32x4 A_3 = *(const f32x4*)&AT[dd + 3][tj * 4];                  \
        const f32x4 B_0 = *(const f32x4*)&BT[dd + 0][ti * 4];                  \
        const f32x4 B_1 = *(const f32x4*)&BT[dd + 1][ti * 4];                  \
        const f32x4 B_2 = *(const f32x4*)&BT[dd + 2][ti * 4];                  \
        const f32x4 B_3 = *(const f32x4*)&BT[dd + 3][ti * 4];                  \
        K2P(ac0l, xy, x); K2P(ac0h, zw, x);                                    \
        K2P(ac1l, xy, y); K2P(ac1h, zw, y);                                    \
        K2P(ac2l, xy, z); K2P(ac2h, zw, z);                                    \
        K2P(ac3l, xy, w); K2P(ac3h, zw, w);                                    \
    }                                                                          \
} while (0)

__global__ __launch_bounds__(256, 4) void k2_scores(
    const float* __restrict__ A0T, const float* __restrict__ A1T,
    const float* __restrict__ B0T, const float* __restrict__ B1T,
    const float* __restrict__ wsc, float* __restrict__ P, int dchunk, float sumf)
{
    __shared__ float at0[32][68], bt0[32][68];
    __shared__ float at1[32][68], bt1[32][68];
    __shared__ float wl[128];
    const int s0 = blockIdx.x * 64;
    const int t0 = blockIdx.y * 64;
    const int dz = blockIdx.z * dchunk;
    const int tid = threadIdx.x;
    if (tid < dchunk) wl[tid] = wsc[dz + tid];
    const int drow = tid >> 3;         // 0..31: d-row within chunk
    const int sc8  = (tid & 7) * 8;    // col offset within 64
    const int ti   = tid >> 4;
    const int tj   = tid & 15;
    const float* __restrict__ Ar0 = A0T + (size_t)(dz + drow) * 512 + s0 + sc8;
    const float* __restrict__ Ar1 = A1T + (size_t)(dz + drow) * 512 + s0 + sc8;
    const float* __restrict__ Br0 = B0T + (size_t)(dz + drow) * 512 + t0 + sc8;
    const float* __restrict__ Br1 = B1T + (size_t)(dz + drow) * 512 + t0 + sc8;
    const f32x2 one2 = splat2(1.f);
    f32x2 ac0l = splat2(0.f), ac0h = splat2(0.f);
    f32x2 ac1l = splat2(0.f), ac1h = splat2(0.f);
    f32x2 ac2l = splat2(0.f), ac2h = splat2(0.f);
    f32x2 ac3l = splat2(0.f), ac3h = splat2(0.f);
    float4 pa00, pa01, pa10, pa11, pb00, pb01, pb10, pb11;
    // prologue: chunk 0 -> buf0
    K2LOAD(0);
    K2WRITE(at0, bt0);
    // dchunk = 128 -> 4 chunks; two dbuf phases per iteration
    for (int c0 = 0; c0 < 4; c0 += 2) {
        __syncthreads();                   // buf0 (chunk c0) ready for all
        K2LOAD(c0 + 1);                    // issue loads; latency under compute
        K2COMP(at0, bt0, c0 * 32);
        K2WRITE(at1, bt1);                 // chunk c0+1 into idle buffer
        __syncthreads();                   // buf1 (chunk c0+1) ready for all
        if (c0 + 2 < 4) {
            K2LOAD(c0 + 2);
            K2COMP(at1, bt1, c0 * 32 + 32);
            K2WRITE(at0, bt0);             // chunk c0+2 into idle buffer
        } else {
            K2COMP(at1, bt1, c0 * 32 + 32);
        }
    }
    float* __restrict__ Pz = P + (size_t)blockIdx.z * 512 * 512;
    float4 o0, o1, o2, o3;
    o0.x = ac0l.x; o0.y = ac0l.y; o0.z = ac0h.x; o0.w = ac0h.y;
    o1.x = ac1l.x; o1.y = ac1l.y; o1.z = ac1h.x; o1.w = ac1h.y;
    o2.x = ac2l.x; o2.y = ac2l.y; o2.z = ac2h.x; o2.w = ac2h.y;
    o3.x = ac3l.x; o3.y = ac3l.y; o3.z = ac3h.x; o3.w = ac3h.y;
    *(float4*)(Pz + (size_t)(t0 + ti * 4 + 0) * 512 + s0 + tj * 4) = o0;
    *(float4*)(Pz + (size_t)(t0 + ti * 4 + 1) * 512 + s0 + tj * 4) = o1;
    *(float4*)(Pz + (size_t)(t0 + ti * 4 + 2) * 512 + s0 + tj * 4) = o2;
    *(float4*)(Pz + (size_t)(t0 + ti * 4 + 3) * 512 + s0 + tj * 4) = o3;
}

// ---- k3: weights[t][:] = softmax_s( -2 * sum_z P_z[t][:] ) ----
__global__ __launch_bounds__(256, 4) void k3_softmax(
    const float* __restrict__ P, float* __restrict__ wgt, int nz)
{
    __shared__ float wm[4];
    __shared__ float wsum[4];
    const int t = blockIdx.x;
    const int tid = threadIdx.x;
    const size_t base = (size_t)t * 512 + tid * 2;
    float sx = 0.f, sy = 0.f;
    for (int z = 0; z < nz; ++z) {
        const float2 p = *(const float2*)(P + base + (size_t)z * 262144);
        sx += p.x; sy += p.y;
    }
    const float x0 = -2.f * sx;
    const float x1 = -2.f * sy;
    float m = fmaxf(x0, x1);
    #pragma unroll
    for (int off = 32; off; off >>= 1) m = fmaxf(m, __shfl_xor(m, off));
    if ((tid & 63) == 0) wm[tid >> 6] = m;
    __syncthreads();
    m = fmaxf(fmaxf(wm[0], wm[1]), fmaxf(wm[2], wm[3]));
    const float L2E = 1.4426950408889634f;
    const float e0 = __builtin_amdgcn_exp2f((x0 - m) * L2E);
    const float e1 = __builtin_amdgcn_exp2f((x1 - m) * L2E);
    float s = e0 + e1;
    #pragma unroll
    for (int off = 32; off; off >>= 1) s += __shfl_xor(s, off);
    if ((tid & 63) == 0) wsum[tid >> 6] = s;
    __syncthreads();
    s = wsum[0] + wsum[1] + wsum[2] + wsum[3];
    const float inv = 1.0f / s;
    float2 o; o.x = e0 * inv; o.y = e1 * inv;
    *(float2*)(wgt + (size_t)t * 512 + tid * 2) = o;
}

// ---- k4_mfma: P4[z] = wgt[:, z*64:(z+1)*64] @ rnn[z*64:(z+1)*64, :] via MFMA ----
#define K4BFRAG(BH, BL, DCOL) do {                                      \
    _Pragma("unroll")                                                   \
    for (int e = 0; e < 8; ++e) {                                       \
        const float v_ = rs[fk + e][(DCOL)];                            \
        const unsigned short h_ = bf16_rne(v_);                         \
        (BH)[e] = (short)h_;                                            \
        (BL)[e] = (short)bf16_rne(v_ - bf16_f(h_));                     \
    }                                                                   \
} while (0)

__global__ __launch_bounds__(256, 4) void k4_mfma(
    const float* __restrict__ wgt, const float* __restrict__ rnn,
    float* __restrict__ P4)
{
    __shared__ unsigned short Gh[64][40], Gl[64][40];
    __shared__ float rs[32][69];
    const int d0g = blockIdx.x * 64;
    const int t0g = blockIdx.y * 64;
    const int z   = blockIdx.z;
    const int tid = threadIdx.x;
    const int lane = tid & 63;
    const int wv = tid >> 6;
    const int tsub = (wv & 1) * 32;
    const int dsub = (wv >> 1) * 32;
    const int trow = tid >> 2, skq = tid & 3;
    const int srw  = tid >> 3, cq  = tid & 7;
    const int frow = lane & 15;
    const int fk   = (lane >> 4) * 8;
    const int sbase = z * 64;
    f32x4 acc00 = {0.f,0.f,0.f,0.f}, acc01 = {0.f,0.f,0.f,0.f};
    f32x4 acc10 = {0.f,0.f,0.f,0.f}, acc11 = {0.f,0.f,0.f,0.f};
    const float* __restrict__ gp = wgt + (size_t)(t0g + trow) * 512 + sbase + skq * 8;
    const float* __restrict__ rp = rnn + (size_t)(sbase + srw) * 512 + d0g + cq * 8;
    float4 g0 = *(const float4*)(gp);
    float4 g1 = *(const float4*)(gp + 4);
    float4 r0 = *(const float4*)(rp);
    float4 r1 = *(const float4*)(rp + 4);
    #pragma unroll
    for (int c = 0; c < 2; ++c) {
        __syncthreads();
        {
            short8 gh8, gl8;
            const float gf[8] = {g0.x,g0.y,g0.z,g0.w,g1.x,g1.y,g1.z,g1.w};
            #pragma unroll
            for (int e = 0; e < 8; ++e) {
                const unsigned short h = bf16_rne(gf[e]);
                gh8[e] = (short)h;
                gl8[e] = (short)bf16_rne(gf[e] - bf16_f(h));
            }
            *(short8*)&Gh[trow][skq * 8] = gh8;
            *(short8*)&Gl[trow][skq * 8] = gl8;
            *(float4*)&rs[srw][cq * 8]     = r0;
            *(float4*)&rs[srw][cq * 8 + 4] = r1;
        }
        __syncthreads();
        if (c == 0) {
            g0 = *(const float4*)(gp + 32);
            g1 = *(const float4*)(gp + 36);
            r0 = *(const float4*)(rp + 32 * 512);
            r1 = *(const float4*)(rp + 32 * 512 + 4);
        }
        const short8 ah0 = *(const short8*)&Gh[tsub + frow][fk];
        const short8 ah1 = *(const short8*)&Gh[tsub + 16 + frow][fk];
        const short8 al0 = *(const short8*)&Gl[tsub + frow][fk];
        const short8 al1 = *(const short8*)&Gl[tsub + 16 + frow][fk];
        short8 bh0, bl0, bh1, bl1;
        K4BFRAG(bh0, bl0, dsub + frow);
        K4BFRAG(bh1, bl1, dsub + 16 + frow);
        acc00 = __builtin_amdgcn_mfma_f32_16x16x32_bf16(ah0, bh0, acc00, 0, 0, 0);
        acc01 = __builtin_amdgcn_mfma_f32_16x16x32_bf16(ah0, bh1, acc01, 0, 0, 0);
        acc10 = __builtin_amdgcn_mfma_f32_16x16x32_bf16(ah1, bh0, acc10, 0, 0, 0);
        acc11 = __builtin_amdgcn_mfma_f32_16x16x32_bf16(ah1, bh1, acc11, 0, 0, 0);
        acc00 = __builtin_amdgcn_mfma_f32_16x16x32_bf16(al0, bh0, acc00, 0, 0, 0);
        acc01 = __builtin_amdgcn_mfma_f32_16x16x32_bf16(al0, bh1, acc01, 0, 0, 0);
        acc10 = __builtin_amdgcn_mfma_f32_16x16x32_bf16(al1, bh0, acc10, 0, 0, 0);
        acc11 = __builtin_amdgcn_mfma_f32_16x16x32_bf16(al1, bh1, acc11, 0, 0, 0);
        acc00 = __builtin_amdgcn_mfma_f32_16x16x32_bf16(ah0, bl0, acc00, 0, 0, 0);
        acc01 = __builtin_amdgcn_mfma_f32_16x16x32_bf16(ah0, bl1, acc01, 0, 0, 0);
        acc10 = __builtin_amdgcn_mfma_f32_16x16x32_bf16(ah1, bl0, acc10, 0, 0, 0);
        acc11 = __builtin_amdgcn_mfma_f32_16x16x32_bf16(ah1, bl1, acc11, 0, 0, 0);
    }
    const int orow = (lane >> 4) * 4;
    const int ocol = lane & 15;
    float* __restrict__ Pz = P4 + (size_t)z * 262144;
#define K4ST(ACC, MT, NT) do {                                           \
    const int tl = tsub + (MT)*16 + orow;                                \
    const int dl = dsub + (NT)*16 + ocol;                                \
    float* p = Pz + (size_t)(t0g + tl) * 512 + d0g + dl;                 \
    p[0]    = ACC[0];                                                    \
    p[512]  = ACC[1];                                                    \
    p[1024] = ACC[2];                                                    \
    p[1536] = ACC[3];                                                    \
} while (0)
    K4ST(acc00, 0, 0); K4ST(acc01, 0, 1); K4ST(acc10, 1, 0); K4ST(acc11, 1, 1);
#undef K4ST
}

// ---- k5: out = sum_{z=0..7} P4[z] ----
__global__ __launch_bounds__(256, 4) void k5_reduce(
    const float* __restrict__ P4, float* __restrict__ out)
{
    const int i = (blockIdx.x * 256 + threadIdx.x) * 4;
    float4 a = *(const float4*)(P4 + i);
    #pragma unroll
    for (int z = 1; z < 8; ++z) {
        const float4 b = *(const float4*)(P4 + (size_t)z * 262144 + i);
        a.x += b.x; a.y += b.y; a.z += b.z; a.w += b.w;
    }
    *(float4*)(out + i) = a;
}

extern "C" void kernel_launch(void* const* d_in, const int* in_sizes, int n_in,
                              void* d_out, int out_size, void* d_ws, size_t ws_size,
                              hipStream_t stream) {
    const float* rnn = (const float*)d_in[0];
    const float* tgt = (const float*)d_in[1];
    const float* W   = (const float*)d_in[2];
    const float* bl  = (const float*)d_in[3];
    const float* wsc = (const float*)d_in[4];
    // d_in[5] (b_score): constant shift under softmax -> unused.
    float* out = (float*)d_out;

    const int nz = 8;
    const int dchunk = 1024 / nz;   // 128
    float* ws = (float*)d_ws;

    // Split path: A0T|A1T|B0T|B1T|P[8]|wgt = (4*524288 + 8*262144 + 262144)*4 = 17,825,792 B
    const bool split = (ws_size >= 17825792u);

    if (split) {
        float* A   = ws;                         // A^T partial 0; partial 1 at +524288
        float* B   = ws + 2 * 524288;            // B^T partial 0; partial 1 at +524288
        float* P   = ws + 4 * 524288;
        float* wgt = P + (size_t)nz * 262144;
        float* P4  = P;                          // alias: P dead after k3
        k1_mfma   <<<dim3(16, 16, 2), 256, 0, stream>>>(rnn, tgt, W, bl, A, B, 2);
        k2_scores <<<dim3(8, 8, nz),  256, 0, stream>>>(A, A + 524288, B, B + 524288,
                                                        wsc, P, dchunk, 1.f);
        k3_softmax<<<512,             256, 0, stream>>>(P, wgt, nz);
        k4_mfma   <<<dim3(8, 8, 8),   256, 0, stream>>>(wgt, rnn, P4);
        k5_reduce <<<256,             256, 0, stream>>>(P4, out);
    } else {
        // Fallback: A^T|B^T|P[8]|wgt = 13.6 MB. k1_mfma unsplit; k2 sumf=0.
        float* A   = ws;
        float* B   = ws + 524288;
        float* P   = ws + 2 * 524288;
        float* wgt = P + (size_t)nz * 262144;
        float* P4  = P;
        k1_mfma   <<<dim3(16, 16, 1), 256, 0, stream>>>(rnn, tgt, W, bl, A, B, 1);
        k2_scores <<<dim3(8, 8, nz),  256, 0, stream>>>(A, A, B, B, wsc, P, dchunk, 0.f);
        k3_softmax<<<512,             256, 0, stream>>>(P, wgt, nz);
        k4_mfma   <<<dim3(8, 8, 8),   256, 0, stream>>>(wgt, rnn, P4);
        k5_reduce <<<256,             256, 0, stream>>>(P4, out);
    }
}

// Round 19
// 55.730 us; speedup vs baseline: 1.0042x; 1.0042x over previous
//
#include <hip/hip_runtime.h>

// Bahdanau additive attention, S=T=512, DU=DT=512, D=1024, fp32.
// score[t,s] = b_s + sum_d w[d]*tanh(A[s,d]+B[t,d]);  out = softmax_s(score) @ rnn
// tanh(x) = 1 - 2/(exp(2x)+1); const shift drops under softmax.
// exp2(C2*(a+b)) = EA[s,d]*EB[t,d]. k1 writes TRANSPOSED partials A^T[d][s];
// k2 staging applies exp2(a0+sumf*a1) (k1b fused). k2 batches 4 d-steps into
// ONE rcp, packed f32x2 cells. k1/k4 use MFMA with bf16 hi/lo split.
// FINAL (champion = R16 config, 55.75us): 5 dispatches.
// Ledger: k2 structure experiments (pack/occupancy/barriers/layout/dbuf) all
// null within ±2us -> k2's 2-barrier staged loop is at its compiler-scheduled
// equilibrium; further gains need inline-asm counted-waitcnt pipelining.
// ws layout (floats): A0T|A1T|B0T|B1T (4x512K) | P[8][256K] | wgt[256K] = 17.8 MB

#define C2F 2.8853900817779268f   // 2*log2(e)

typedef __attribute__((ext_vector_type(8))) short short8;
typedef __attribute__((ext_vector_type(4))) float f32x4;
typedef __attribute__((ext_vector_type(2))) float f32x2;

__device__ __forceinline__ unsigned short bf16_rne(float f) {
    unsigned u = __builtin_bit_cast(unsigned, f);
    unsigned r = (u + 0x7FFFu + ((u >> 16) & 1u)) >> 16;
    return (unsigned short)r;
}
__device__ __forceinline__ float bf16_f(unsigned short h) {
    unsigned u = ((unsigned)h) << 16;
    return __builtin_bit_cast(float, u);
}
__device__ __forceinline__ f32x2 splat2(float s) {
    f32x2 r; r.x = s; r.y = s; return r;
}

// ---- k1_mfma: partial GEMM via MFMA, TRANSPOSED output X^T[j][i].
// i in [0,1024): i<512 -> A (in=rnn), else B (in=tgt, +bias last kz).
__global__ __launch_bounds__(256, 4) void k1_mfma(
    const float* __restrict__ rnn, const float* __restrict__ tgt,
    const float* __restrict__ W, const float* __restrict__ bl,
    float* __restrict__ Abuf, float* __restrict__ Bbuf, int ksplit)
{
    __shared__ unsigned short Xh[64][40], Xl[64][40], Wh[64][40], Wl[64][40];
    const int j0 = blockIdx.x * 64;
    const int i0 = blockIdx.y * 64;
    const int kz = blockIdx.z;
    const int klen = 512 / ksplit;
    const int kbase = kz * klen;
    const bool isB = (i0 >= 512);
    const float* __restrict__ X = isB ? tgt : rnn;
    const int irow0 = isB ? (i0 - 512) : i0;
    const int koff = isB ? 512 : 0;
    const int tid = threadIdx.x;
    const int lane = tid & 63;
    const int wv = tid >> 6;
    const int isub = (wv & 1) * 32;
    const int jsub = (wv >> 1) * 32;
    const int srow = tid >> 2;
    const int skq  = tid & 3;
    const float* __restrict__ xp = X + (size_t)(irow0 + srow) * 512 + kbase + skq * 8;
    const float* __restrict__ wp = W + (size_t)(j0 + srow) * 1024 + koff + kbase + skq * 8;
    const int frow = lane & 15;
    const int fk   = (lane >> 4) * 8;
    f32x4 acc00 = {0.f,0.f,0.f,0.f}, acc01 = {0.f,0.f,0.f,0.f};
    f32x4 acc10 = {0.f,0.f,0.f,0.f}, acc11 = {0.f,0.f,0.f,0.f};
    float4 xv0 = *(const float4*)(xp);
    float4 xv1 = *(const float4*)(xp + 4);
    float4 wv0 = *(const float4*)(wp);
    float4 wv1 = *(const float4*)(wp + 4);
    for (int k0 = 0; k0 < klen; k0 += 32) {
        __syncthreads();
        {
            short8 xh8, xl8, wh8, wl8;
            const float xf[8] = {xv0.x, xv0.y, xv0.z, xv0.w, xv1.x, xv1.y, xv1.z, xv1.w};
            const float wf[8] = {wv0.x, wv0.y, wv0.z, wv0.w, wv1.x, wv1.y, wv1.z, wv1.w};
            #pragma unroll
            for (int e = 0; e < 8; ++e) {
                const unsigned short xh = bf16_rne(xf[e]);
                const unsigned short wh = bf16_rne(wf[e]);
                xh8[e] = (short)xh;
                wh8[e] = (short)wh;
                xl8[e] = (short)bf16_rne(xf[e] - bf16_f(xh));
                wl8[e] = (short)bf16_rne(wf[e] - bf16_f(wh));
            }
            *(short8*)&Xh[srow][skq * 8] = xh8;
            *(short8*)&Xl[srow][skq * 8] = xl8;
            *(short8*)&Wh[srow][skq * 8] = wh8;
            *(short8*)&Wl[srow][skq * 8] = wl8;
        }
        __syncthreads();
        if (k0 + 32 < klen) {
            xv0 = *(const float4*)(xp + k0 + 32);
            xv1 = *(const float4*)(xp + k0 + 36);
            wv0 = *(const float4*)(wp + k0 + 32);
            wv1 = *(const float4*)(wp + k0 + 36);
        }
        const short8 ah0 = *(const short8*)&Xh[isub + frow][fk];
        const short8 ah1 = *(const short8*)&Xh[isub + 16 + frow][fk];
        const short8 bh0 = *(const short8*)&Wh[jsub + frow][fk];
        const short8 bh1 = *(const short8*)&Wh[jsub + 16 + frow][fk];
        acc00 = __builtin_amdgcn_mfma_f32_16x16x32_bf16(ah0, bh0, acc00, 0, 0, 0);
        acc01 = __builtin_amdgcn_mfma_f32_16x16x32_bf16(ah0, bh1, acc01, 0, 0, 0);
        acc10 = __builtin_amdgcn_mfma_f32_16x16x32_bf16(ah1, bh0, acc10, 0, 0, 0);
        acc11 = __builtin_amdgcn_mfma_f32_16x16x32_bf16(ah1, bh1, acc11, 0, 0, 0);
        const short8 al0 = *(const short8*)&Xl[isub + frow][fk];
        const short8 al1 = *(const short8*)&Xl[isub + 16 + frow][fk];
        acc00 = __builtin_amdgcn_mfma_f32_16x16x32_bf16(al0, bh0, acc00, 0, 0, 0);
        acc01 = __builtin_amdgcn_mfma_f32_16x16x32_bf16(al0, bh1, acc01, 0, 0, 0);
        acc10 = __builtin_amdgcn_mfma_f32_16x16x32_bf16(al1, bh0, acc10, 0, 0, 0);
        acc11 = __builtin_amdgcn_mfma_f32_16x16x32_bf16(al1, bh1, acc11, 0, 0, 0);
        const short8 bl0 = *(const short8*)&Wl[jsub + frow][fk];
        const short8 bl1 = *(const short8*)&Wl[jsub + 16 + frow][fk];
        acc00 = __builtin_amdgcn_mfma_f32_16x16x32_bf16(ah0, bl0, acc00, 0, 0, 0);
        acc01 = __builtin_amdgcn_mfma_f32_16x16x32_bf16(ah0, bl1, acc01, 0, 0, 0);
        acc10 = __builtin_amdgcn_mfma_f32_16x16x32_bf16(ah1, bl0, acc10, 0, 0, 0);
        acc11 = __builtin_amdgcn_mfma_f32_16x16x32_bf16(ah1, bl1, acc11, 0, 0, 0);
    }
    const int orow = (lane >> 4) * 4;
    const int ocol = lane & 15;
    float* __restrict__ dst = (isB ? Bbuf : Abuf) + (size_t)kz * 524288;
    const bool addb = isB && (kz == ksplit - 1);
#define K1ST(ACC, MT, NT) do {                                            \
    const int jl = jsub + (NT)*16 + ocol;                                 \
    const float bb = addb ? bl[j0 + jl] : 0.f;                            \
    const int il = isub + (MT)*16 + orow;                                 \
    float4 o;                                                             \
    o.x = (ACC[0] + bb) * C2F;                                            \
    o.y = (ACC[1] + bb) * C2F;                                            \
    o.z = (ACC[2] + bb) * C2F;                                            \
    o.w = (ACC[3] + bb) * C2F;                                            \
    *(float4*)(dst + (size_t)(j0 + jl) * 512 + irow0 + il) = o;           \
} while (0)
    K1ST(acc00, 0, 0); K1ST(acc01, 0, 1); K1ST(acc10, 1, 0); K1ST(acc11, 1, 1);
#undef K1ST
}

// ---- k2 (hot): P[z][t][s] = sum_{d in chunk z} w[d] / (EA[s,d]*EB[t,d] + 1) ----
// EA/EB computed in staging from transposed partials: exp2(a0 + sumf*a1),
// coalesced row loads, b128 LDS writes. 64x64 tile, 4x4 micro, nz=8.
// 4 d-steps share ONE rcp; cell pairs packed as f32x2 (v_pk_fma_f32).
#define K2P(ACC, PP, RR) do {                                                  \
    const f32x2 e0_ = __builtin_elementwise_fma(A0.PP, splat2(B0.RR), one2);   \
    const f32x2 e1_ = __builtin_elementwise_fma(A1.PP, splat2(B1.RR), one2);   \
    const f32x2 e2_ = __builtin_elementwise_fma(A2.PP, splat2(B2.RR), one2);   \
    const f32x2 e3_ = __builtin_elementwise_fma(A3.PP, splat2(B3.RR), one2);   \
    const f32x2 l01_ = e0_ * e1_;                                              \
    const f32x2 l23_ = e2_ * e3_;                                              \
    const f32x2 n01_ = __builtin_elementwise_fma(wx2, e1_, wy2 * e0_);         \
    const f32x2 n23_ = __builtin_elementwise_fma(wz2, e3_, ww2 * e2_);         \
    const f32x2 N_   = __builtin_elementwise_fma(n01_, l23_, n23_ * l01_);     \
    const f32x2 D_   = l01_ * l23_;                                            \
    f32x2 rd_;                                                                 \
    rd_.x = __builtin_amdgcn_rcpf(D_.x);                                       \
    rd_.y = __builtin_amdgcn_rcpf(D_.y);                                       \
    ACC = __builtin_elementwise_fma(N_, rd_, ACC);                             \
} while (0)

#define K2EXP(P0, P1) __builtin_amdgcn_exp2f(__builtin_fmaf(sumf, (P1), (P0)))

__global__ __launch_bounds__(256, 4) void k2_scores(
    const float* __restrict__ A0T, const float* __restrict__ A1T,
    const float* __restrict__ B0T, const float* __restrict__ B1T,
    const float* __restrict__ wsc, float* __restrict__ P, int dchunk, float sumf)
{
    __shared__ float at[32][68];   // [d][s]
    __shared__ float bt[32][68];   // [d][t]
    __shared__ float wl[128];
    const int s0 = blockIdx.x * 64;
    const int t0 = blockIdx.y * 64;
    const int dz = blockIdx.z * dchunk;
    const int tid = threadIdx.x;
    if (tid < dchunk) wl[tid] = wsc[dz + tid];
    const int drow = tid >> 3;         // 0..31: d-row within chunk
    const int sc8  = (tid & 7) * 8;    // col offset within 64
    const int ti   = tid >> 4;
    const int tj   = tid & 15;
    const float* __restrict__ Ar0 = A0T + (size_t)(dz + drow) * 512 + s0 + sc8;
    const float* __restrict__ Ar1 = A1T + (size_t)(dz + drow) * 512 + s0 + sc8;
    const float* __restrict__ Br0 = B0T + (size_t)(dz + drow) * 512 + t0 + sc8;
    const float* __restrict__ Br1 = B1T + (size_t)(dz + drow) * 512 + t0 + sc8;
    const f32x2 one2 = splat2(1.f);
    f32x2 ac0l = splat2(0.f), ac0h = splat2(0.f);
    f32x2 ac1l = splat2(0.f), ac1h = splat2(0.f);
    f32x2 ac2l = splat2(0.f), ac2h = splat2(0.f);
    f32x2 ac3l = splat2(0.f), ac3h = splat2(0.f);
    float4 pa00 = *(const float4*)(Ar0);
    float4 pa01 = *(const float4*)(Ar0 + 4);
    float4 pa10 = *(const float4*)(Ar1);
    float4 pa11 = *(const float4*)(Ar1 + 4);
    float4 pb00 = *(const float4*)(Br0);
    float4 pb01 = *(const float4*)(Br0 + 4);
    float4 pb10 = *(const float4*)(Br1);
    float4 pb11 = *(const float4*)(Br1 + 4);
    for (int c0 = 0; c0 < dchunk; c0 += 32) {
        __syncthreads();   // previous chunk's readers done
        {
            float4 ea0, ea1, eb0, eb1;
            ea0.x = K2EXP(pa00.x, pa10.x);
            ea0.y = K2EXP(pa00.y, pa10.y);
            ea0.z = K2EXP(pa00.z, pa10.z);
            ea0.w = K2EXP(pa00.w, pa10.w);
            ea1.x = K2EXP(pa01.x, pa11.x);
            ea1.y = K2EXP(pa01.y, pa11.y);
            ea1.z = K2EXP(pa01.z, pa11.z);
            ea1.w = K2EXP(pa01.w, pa11.w);
            eb0.x = K2EXP(pb00.x, pb10.x);
            eb0.y = K2EXP(pb00.y, pb10.y);
            eb0.z = K2EXP(pb00.z, pb10.z);
            eb0.w = K2EXP(pb00.w, pb10.w);
            eb1.x = K2EXP(pb01.x, pb11.x);
            eb1.y = K2EXP(pb01.y, pb11.y);
            eb1.z = K2EXP(pb01.z, pb11.z);
            eb1.w = K2EXP(pb01.w, pb11.w);
            *(float4*)&at[drow][sc8]     = ea0;
            *(float4*)&at[drow][sc8 + 4] = ea1;
            *(float4*)&bt[drow][sc8]     = eb0;
            *(float4*)&bt[drow][sc8 + 4] = eb1;
        }
        __syncthreads();
        if (c0 + 32 < dchunk) {            // prefetch next chunk under compute
            const size_t off = (size_t)(c0 + 32) * 512;
            pa00 = *(const float4*)(Ar0 + off);
            pa01 = *(const float4*)(Ar0 + off + 4);
            pa10 = *(const float4*)(Ar1 + off);
            pa11 = *(const float4*)(Ar1 + off + 4);
            pb00 = *(const float4*)(Br0 + off);
            pb01 = *(const float4*)(Br0 + off + 4);
            pb10 = *(const float4*)(Br1 + off);
            pb11 = *(const float4*)(Br1 + off + 4);
        }
        for (int dd = 0; dd < 32; dd += 4) {
            const float4 wa = *(const float4*)&wl[c0 + dd];
            const f32x2 wx2 = splat2(wa.x);
            const f32x2 wy2 = splat2(wa.y);
            const f32x2 wz2 = splat2(wa.z);
            const f32x2 ww2 = splat2(wa.w);
            const f32x4 A0 = *(const f32x4*)&at[dd + 0][tj * 4];
            const f32x4 A1 = *(const f32x4*)&at[dd + 1][tj * 4];
            const f32x4 A2 = *(const f32x4*)&at[dd + 2][tj * 4];
            const f32x4 A3 = *(const f32x4*)&at[dd + 3][tj * 4];
            const f32x4 B0 = *(const f32x4*)&bt[dd + 0][ti * 4];
            const f32x4 B1 = *(const f32x4*)&bt[dd + 1][ti * 4];
            const f32x4 B2 = *(const f32x4*)&bt[dd + 2][ti * 4];
            const f32x4 B3 = *(const f32x4*)&bt[dd + 3][ti * 4];
            K2P(ac0l, xy, x); K2P(ac0h, zw, x);
            K2P(ac1l, xy, y); K2P(ac1h, zw, y);
            K2P(ac2l, xy, z); K2P(ac2h, zw, z);
            K2P(ac3l, xy, w); K2P(ac3h, zw, w);
        }
    }
    float* __restrict__ Pz = P + (size_t)blockIdx.z * 512 * 512;
    float4 o0, o1, o2, o3;
    o0.x = ac0l.x; o0.y = ac0l.y; o0.z = ac0h.x; o0.w = ac0h.y;
    o1.x = ac1l.x; o1.y = ac1l.y; o1.z = ac1h.x; o1.w = ac1h.y;
    o2.x = ac2l.x; o2.y = ac2l.y; o2.z = ac2h.x; o2.w = ac2h.y;
    o3.x = ac3l.x; o3.y = ac3l.y; o3.z = ac3h.x; o3.w = ac3h.y;
    *(float4*)(Pz + (size_t)(t0 + ti * 4 + 0) * 512 + s0 + tj * 4) = o0;
    *(float4*)(Pz + (size_t)(t0 + ti * 4 + 1) * 512 + s0 + tj * 4) = o1;
    *(float4*)(Pz + (size_t)(t0 + ti * 4 + 2) * 512 + s0 + tj * 4) = o2;
    *(float4*)(Pz + (size_t)(t0 + ti * 4 + 3) * 512 + s0 + tj * 4) = o3;
}

// ---- k3: weights[t][:] = softmax_s( -2 * sum_z P_z[t][:] ) ----
__global__ __launch_bounds__(256, 4) void k3_softmax(
    const float* __restrict__ P, float* __restrict__ wgt, int nz)
{
    __shared__ float wm[4];
    __shared__ float wsum[4];
    const int t = blockIdx.x;
    const int tid = threadIdx.x;
    const size_t base = (size_t)t * 512 + tid * 2;
    float sx = 0.f, sy = 0.f;
    for (int z = 0; z < nz; ++z) {
        const float2 p = *(const float2*)(P + base + (size_t)z * 262144);
        sx += p.x; sy += p.y;
    }
    const float x0 = -2.f * sx;
    const float x1 = -2.f * sy;
    float m = fmaxf(x0, x1);
    #pragma unroll
    for (int off = 32; off; off >>= 1) m = fmaxf(m, __shfl_xor(m, off));
    if ((tid & 63) == 0) wm[tid >> 6] = m;
    __syncthreads();
    m = fmaxf(fmaxf(wm[0], wm[1]), fmaxf(wm[2], wm[3]));
    const float L2E = 1.4426950408889634f;
    const float e0 = __builtin_amdgcn_exp2f((x0 - m) * L2E);
    const float e1 = __builtin_amdgcn_exp2f((x1 - m) * L2E);
    float s = e0 + e1;
    #pragma unroll
    for (int off = 32; off; off >>= 1) s += __shfl_xor(s, off);
    if ((tid & 63) == 0) wsum[tid >> 6] = s;
    __syncthreads();
    s = wsum[0] + wsum[1] + wsum[2] + wsum[3];
    const float inv = 1.0f / s;
    float2 o; o.x = e0 * inv; o.y = e1 * inv;
    *(float2*)(wgt + (size_t)t * 512 + tid * 2) = o;
}

// ---- k4_mfma: P4[z] = wgt[:, z*64:(z+1)*64] @ rnn[z*64:(z+1)*64, :] via MFMA ----
#define K4BFRAG(BH, BL, DCOL) do {                                      \
    _Pragma("unroll")                                                   \
    for (int e = 0; e < 8; ++e) {                                       \
        const float v_ = rs[fk + e][(DCOL)];                            \
        const unsigned short h_ = bf16_rne(v_);                         \
        (BH)[e] = (short)h_;                                            \
        (BL)[e] = (short)bf16_rne(v_ - bf16_f(h_));                     \
    }                                                                   \
} while (0)

__global__ __launch_bounds__(256, 4) void k4_mfma(
    const float* __restrict__ wgt, const float* __restrict__ rnn,
    float* __restrict__ P4)
{
    __shared__ unsigned short Gh[64][40], Gl[64][40];
    __shared__ float rs[32][69];
    const int d0g = blockIdx.x * 64;
    const int t0g = blockIdx.y * 64;
    const int z   = blockIdx.z;
    const int tid = threadIdx.x;
    const int lane = tid & 63;
    const int wv = tid >> 6;
    const int tsub = (wv & 1) * 32;
    const int dsub = (wv >> 1) * 32;
    const int trow = tid >> 2, skq = tid & 3;
    const int srw  = tid >> 3, cq  = tid & 7;
    const int frow = lane & 15;
    const int fk   = (lane >> 4) * 8;
    const int sbase = z * 64;
    f32x4 acc00 = {0.f,0.f,0.f,0.f}, acc01 = {0.f,0.f,0.f,0.f};
    f32x4 acc10 = {0.f,0.f,0.f,0.f}, acc11 = {0.f,0.f,0.f,0.f};
    const float* __restrict__ gp = wgt + (size_t)(t0g + trow) * 512 + sbase + skq * 8;
    const float* __restrict__ rp = rnn + (size_t)(sbase + srw) * 512 + d0g + cq * 8;
    float4 g0 = *(const float4*)(gp);
    float4 g1 = *(const float4*)(gp + 4);
    float4 r0 = *(const float4*)(rp);
    float4 r1 = *(const float4*)(rp + 4);
    #pragma unroll
    for (int c = 0; c < 2; ++c) {
        __syncthreads();
        {
            short8 gh8, gl8;
            const float gf[8] = {g0.x,g0.y,g0.z,g0.w,g1.x,g1.y,g1.z,g1.w};
            #pragma unroll
            for (int e = 0; e < 8; ++e) {
                const unsigned short h = bf16_rne(gf[e]);
                gh8[e] = (short)h;
                gl8[e] = (short)bf16_rne(gf[e] - bf16_f(h));
            }
            *(short8*)&Gh[trow][skq * 8] = gh8;
            *(short8*)&Gl[trow][skq * 8] = gl8;
            *(float4*)&rs[srw][cq * 8]     = r0;
            *(float4*)&rs[srw][cq * 8 + 4] = r1;
        }
        __syncthreads();
        if (c == 0) {
            g0 = *(const float4*)(gp + 32);
            g1 = *(const float4*)(gp + 36);
            r0 = *(const float4*)(rp + 32 * 512);
            r1 = *(const float4*)(rp + 32 * 512 + 4);
        }
        const short8 ah0 = *(const short8*)&Gh[tsub + frow][fk];
        const short8 ah1 = *(const short8*)&Gh[tsub + 16 + frow][fk];
        const short8 al0 = *(const short8*)&Gl[tsub + frow][fk];
        const short8 al1 = *(const short8*)&Gl[tsub + 16 + frow][fk];
        short8 bh0, bl0, bh1, bl1;
        K4BFRAG(bh0, bl0, dsub + frow);
        K4BFRAG(bh1, bl1, dsub + 16 + frow);
        acc00 = __builtin_amdgcn_mfma_f32_16x16x32_bf16(ah0, bh0, acc00, 0, 0, 0);
        acc01 = __builtin_amdgcn_mfma_f32_16x16x32_bf16(ah0, bh1, acc01, 0, 0, 0);
        acc10 = __builtin_amdgcn_mfma_f32_16x16x32_bf16(ah1, bh0, acc10, 0, 0, 0);
        acc11 = __builtin_amdgcn_mfma_f32_16x16x32_bf16(ah1, bh1, acc11, 0, 0, 0);
        acc00 = __builtin_amdgcn_mfma_f32_16x16x32_bf16(al0, bh0, acc00, 0, 0, 0);
        acc01 = __builtin_amdgcn_mfma_f32_16x16x32_bf16(al0, bh1, acc01, 0, 0, 0);
        acc10 = __builtin_amdgcn_mfma_f32_16x16x32_bf16(al1, bh0, acc10, 0, 0, 0);
        acc11 = __builtin_amdgcn_mfma_f32_16x16x32_bf16(al1, bh1, acc11, 0, 0, 0);
        acc00 = __builtin_amdgcn_mfma_f32_16x16x32_bf16(ah0, bl0, acc00, 0, 0, 0);
        acc01 = __builtin_amdgcn_mfma_f32_16x16x32_bf16(ah0, bl1, acc01, 0, 0, 0);
        acc10 = __builtin_amdgcn_mfma_f32_16x16x32_bf16(ah1, bl0, acc10, 0, 0, 0);
        acc11 = __builtin_amdgcn_mfma_f32_16x16x32_bf16(ah1, bl1, acc11, 0, 0, 0);
    }
    const int orow = (lane >> 4) * 4;
    const int ocol = lane & 15;
    float* __restrict__ Pz = P4 + (size_t)z * 262144;
#define K4ST(ACC, MT, NT) do {                                           \
    const int tl = tsub + (MT)*16 + orow;                                \
    const int dl = dsub + (NT)*16 + ocol;                                \
    float* p = Pz + (size_t)(t0g + tl) * 512 + d0g + dl;                 \
    p[0]    = ACC[0];                                                    \
    p[512]  = ACC[1];                                                    \
    p[1024] = ACC[2];                                                    \
    p[1536] = ACC[3];                                                    \
} while (0)
    K4ST(acc00, 0, 0); K4ST(acc01, 0, 1); K4ST(acc10, 1, 0); K4ST(acc11, 1, 1);
#undef K4ST
}

// ---- k5: out = sum_{z=0..7} P4[z] ----
__global__ __launch_bounds__(256, 4) void k5_reduce(
    const float* __restrict__ P4, float* __restrict__ out)
{
    const int i = (blockIdx.x * 256 + threadIdx.x) * 4;
    float4 a = *(const float4*)(P4 + i);
    #pragma unroll
    for (int z = 1; z < 8; ++z) {
        const float4 b = *(const float4*)(P4 + (size_t)z * 262144 + i);
        a.x += b.x; a.y += b.y; a.z += b.z; a.w += b.w;
    }
    *(float4*)(out + i) = a;
}

extern "C" void kernel_launch(void* const* d_in, const int* in_sizes, int n_in,
                              void* d_out, int out_size, void* d_ws, size_t ws_size,
                              hipStream_t stream) {
    const float* rnn = (const float*)d_in[0];
    const float* tgt = (const float*)d_in[1];
    const float* W   = (const float*)d_in[2];
    const float* bl  = (const float*)d_in[3];
    const float* wsc = (const float*)d_in[4];
    // d_in[5] (b_score): constant shift under softmax -> unused.
    float* out = (float*)d_out;

    const int nz = 8;
    const int dchunk = 1024 / nz;   // 128
    float* ws = (float*)d_ws;

    // Split path: A0T|A1T|B0T|B1T|P[8]|wgt = (4*524288 + 8*262144 + 262144)*4 = 17,825,792 B
    const bool split = (ws_size >= 17825792u);

    if (split) {
        float* A   = ws;                         // A^T partial 0; partial 1 at +524288
        float* B   = ws + 2 * 524288;            // B^T partial 0; partial 1 at +524288
        float* P   = ws + 4 * 524288;
        float* wgt = P + (size_t)nz * 262144;
        float* P4  = P;                          // alias: P dead after k3
        k1_mfma   <<<dim3(16, 16, 2), 256, 0, stream>>>(rnn, tgt, W, bl, A, B, 2);
        k2_scores <<<dim3(8, 8, nz),  256, 0, stream>>>(A, A + 524288, B, B + 524288,
                                                        wsc, P, dchunk, 1.f);
        k3_softmax<<<512,             256, 0, stream>>>(P, wgt, nz);
        k4_mfma   <<<dim3(8, 8, 8),   256, 0, stream>>>(wgt, rnn, P4);
        k5_reduce <<<256,             256, 0, stream>>>(P4, out);
    } else {
        // Fallback: A^T|B^T|P[8]|wgt = 13.6 MB. k1_mfma unsplit; k2 sumf=0.
        float* A   = ws;
        float* B   = ws + 524288;
        float* P   = ws + 2 * 524288;
        float* wgt = P + (size_t)nz * 262144;
        float* P4  = P;
        k1_mfma   <<<dim3(16, 16, 1), 256, 0, stream>>>(rnn, tgt, W, bl, A, B, 1);
        k2_scores <<<dim3(8, 8, nz),  256, 0, stream>>>(A, A, B, B, wsc, P, dchunk, 0.f);
        k3_softmax<<<512,             256, 0, stream>>>(P, wgt, nz);
        k4_mfma   <<<dim3(8, 8, 8),   256, 0, stream>>>(wgt, rnn, P4);
        k5_reduce <<<256,             256, 0, stream>>>(P4, out);
    }
}